// Round 3
// baseline (310.018 us; speedup 1.0000x reference)
//
#include <hip/hip_runtime.h>
#include <hip/hip_bf16.h>

#define NN 50000
#define NE 800000
#define NF 96
#define NH 128
#define NC 40

// ---------------- workspace layout (bytes) ----------------
// deg    : int[NN]        @ 0
// start  : int[NN]        @ 200192
// cursor : int[NN]        @ 400384
// norm   : float[NN]      @ 600576
// gctr   : int[1]         @ 800768
// M      : float[2*40*96] @ 801280   (M1 then M2, row-major [m][c][j])
// col    : int[NE]        @ 832000
// h1     : float[NN*NF]   @ 4032000
// h2     : float[NN*NF]   @ 23232000
// total  : 42,432,000 bytes

__global__ void deg_count(const int* __restrict__ dst, int* __restrict__ deg) {
    int e = blockIdx.x * blockDim.x + threadIdx.x;
    if (e < NE) atomicAdd(&deg[dst[e]], 1);
}

// norm + unordered-CSR slab reservation (wave-aggregated atomic)
__global__ void norm_reserve(const int* __restrict__ deg, float* __restrict__ norm,
                             int* __restrict__ start, int* __restrict__ cursor,
                             int* __restrict__ gctr) {
    int v = blockIdx.x * blockDim.x + threadIdx.x;
    int d = (v < NN) ? deg[v] : 0;
    if (v < NN) norm[v] = (d > 0) ? (1.0f / sqrtf((float)d)) : 1.0f;
    // wave-64 inclusive scan of d
    int lane = threadIdx.x & 63;
    int incl = d;
    #pragma unroll
    for (int off = 1; off < 64; off <<= 1) {
        int n = __shfl_up(incl, off);
        if (lane >= off) incl += n;
    }
    int total = __shfl(incl, 63);
    int base = 0;
    if (lane == 63) base = atomicAdd(gctr, total);
    base = __shfl(base, 63);
    int st = base + incl - d;   // exclusive prefix + slab base
    if (v < NN) { start[v] = st; cursor[v] = st; }
}

__global__ void fill_csr(const int* __restrict__ src, const int* __restrict__ dst,
                         int* __restrict__ cursor, int* __restrict__ col) {
    int e = blockIdx.x * blockDim.x + threadIdx.x;
    if (e < NE) {
        int p = atomicAdd(&cursor[dst[e]], 1);
        col[p] = src[e];
    }
}

// M1[c][j] = sum_k Wproj[c][k]     * Wlin[k][j]
// M2[c][j] = sum_k Wproj[c][128+k] * Wsgc[k][j]
__global__ void make_m(const float* __restrict__ Wsgc, const float* __restrict__ Wlin,
                       const float* __restrict__ Wproj, float* __restrict__ M) {
    int t = blockIdx.x * blockDim.x + threadIdx.x;
    if (t >= 2 * NC * NF) return;
    int m = t / (NC * NF);
    int r = t % (NC * NF);
    int c = r / NF, j = r % NF;
    const float* A  = m ? Wsgc : Wlin;
    const float* wp = Wproj + c * (2 * NH) + m * NH;
    float acc = 0.f;
    #pragma unroll 4
    for (int k = 0; k < NH; ++k) acc = fmaf(wp[k], A[k * NF + j], acc);
    M[t] = acc;
}

// out[v] = norm[v] * sum_{p in row v} norm[col[p]] * in[col[p]]
// 8 lanes cooperate per node: lane L owns float4 slots {L, L+8, L+16} of the
// 24-float4 row. Per-edge loads are three 128B-contiguous 8-lane segments.
__global__ __launch_bounds__(256) void spmm(const float* __restrict__ hin,
                                            float* __restrict__ hout,
                                            const float* __restrict__ norm,
                                            const int* __restrict__ start,
                                            const int* __restrict__ deg,
                                            const int* __restrict__ col) {
    int t = blockIdx.x * blockDim.x + threadIdx.x;
    int v = t >> 3;
    int lane = t & 7;
    if (v >= NN) return;
    float4 a0 = make_float4(0.f, 0.f, 0.f, 0.f);
    float4 a1 = a0, a2 = a0;
    int p0 = start[v], d = deg[v];
    const float4* base = (const float4*)hin;
    for (int p = p0; p < p0 + d; ++p) {
        int s = col[p];            // same address across the 8-lane group: broadcast
        float w = norm[s];
        const float4* row = base + (size_t)s * (NF / 4);
        float4 r0 = row[lane];
        float4 r1 = row[lane + 8];
        float4 r2 = row[lane + 16];
        a0.x = fmaf(w, r0.x, a0.x); a0.y = fmaf(w, r0.y, a0.y);
        a0.z = fmaf(w, r0.z, a0.z); a0.w = fmaf(w, r0.w, a0.w);
        a1.x = fmaf(w, r1.x, a1.x); a1.y = fmaf(w, r1.y, a1.y);
        a1.z = fmaf(w, r1.z, a1.z); a1.w = fmaf(w, r1.w, a1.w);
        a2.x = fmaf(w, r2.x, a2.x); a2.y = fmaf(w, r2.y, a2.y);
        a2.z = fmaf(w, r2.z, a2.z); a2.w = fmaf(w, r2.w, a2.w);
    }
    float nv = norm[v];
    float4* orow = (float4*)hout + (size_t)v * (NF / 4);
    float4 o0 = make_float4(nv * a0.x, nv * a0.y, nv * a0.z, nv * a0.w);
    float4 o1 = make_float4(nv * a1.x, nv * a1.y, nv * a1.z, nv * a1.w);
    float4 o2 = make_float4(nv * a2.x, nv * a2.y, nv * a2.z, nv * a2.w);
    orow[lane]      = o0;
    orow[lane + 8]  = o1;
    orow[lane + 16] = o2;
}

// out[v][c] = dot(f[v], M1[c]) + dot(h2[v], M2[c])
// block = 256 threads; thread: part = tid&3 (10 classes), handles 4 nodes.
// block covers 256 nodes.
__global__ __launch_bounds__(256) void final_gemm(const float* __restrict__ f,
                                                  const float* __restrict__ h2,
                                                  const float* __restrict__ M,
                                                  float* __restrict__ out) {
    __shared__ float Ml[2 * NC * NF];
    for (int i = threadIdx.x; i < 2 * NC * NF; i += 256) Ml[i] = M[i];
    __syncthreads();

    int part = threadIdx.x & 3;
    int grp  = threadIdx.x >> 2;
    int vb = blockIdx.x * 256 + grp * 4;

    float acc[4][10];
    #pragma unroll
    for (int n = 0; n < 4; ++n)
        #pragma unroll
        for (int c = 0; c < 10; ++c) acc[n][c] = 0.f;

    const float4* M1 = (const float4*)(Ml);            // [40][24]
    const float4* M2 = (const float4*)(Ml + NC * NF);  // [40][24]
    int c0 = part * 10;

    for (int j4 = 0; j4 < NF / 4; ++j4) {
        float4 fr[4], hr[4];
        #pragma unroll
        for (int n = 0; n < 4; ++n) {
            int v = vb + n;
            if (v < NN) {
                fr[n] = ((const float4*)(f  + (size_t)v * NF))[j4];
                hr[n] = ((const float4*)(h2 + (size_t)v * NF))[j4];
            } else {
                fr[n] = make_float4(0.f, 0.f, 0.f, 0.f);
                hr[n] = make_float4(0.f, 0.f, 0.f, 0.f);
            }
        }
        #pragma unroll
        for (int cc = 0; cc < 10; ++cc) {
            float4 a = M1[(c0 + cc) * (NF / 4) + j4];
            float4 b = M2[(c0 + cc) * (NF / 4) + j4];
            #pragma unroll
            for (int n = 0; n < 4; ++n) {
                float t = acc[n][cc];
                t = fmaf(fr[n].x, a.x, t);
                t = fmaf(fr[n].y, a.y, t);
                t = fmaf(fr[n].z, a.z, t);
                t = fmaf(fr[n].w, a.w, t);
                t = fmaf(hr[n].x, b.x, t);
                t = fmaf(hr[n].y, b.y, t);
                t = fmaf(hr[n].z, b.z, t);
                t = fmaf(hr[n].w, b.w, t);
                acc[n][cc] = t;
            }
        }
    }
    #pragma unroll
    for (int n = 0; n < 4; ++n) {
        int v = vb + n;
        if (v < NN) {
            #pragma unroll
            for (int cc = 0; cc < 10; ++cc)
                out[(size_t)v * NC + c0 + cc] = acc[n][cc];
        }
    }
}

extern "C" void kernel_launch(void* const* d_in, const int* in_sizes, int n_in,
                              void* d_out, int out_size, void* d_ws, size_t ws_size,
                              hipStream_t stream) {
    const float* feat  = (const float*)d_in[0];
    const int*   src   = (const int*)d_in[1];
    const int*   dst   = (const int*)d_in[2];
    const float* Wsgc  = (const float*)d_in[3];
    const float* Wlin  = (const float*)d_in[4];
    const float* Wproj = (const float*)d_in[5];
    float* out = (float*)d_out;
    char* ws = (char*)d_ws;

    int*   deg    = (int*)(ws + 0);
    int*   start  = (int*)(ws + 200192);
    int*   cursor = (int*)(ws + 400384);
    float* norm   = (float*)(ws + 600576);
    int*   gctr   = (int*)(ws + 800768);
    float* M      = (float*)(ws + 801280);
    int*   col    = (int*)(ws + 832000);
    float* h1     = (float*)(ws + 4032000);
    float* h2     = (float*)(ws + 23232000);

    hipMemsetAsync(deg, 0, NN * sizeof(int), stream);
    hipMemsetAsync(gctr, 0, sizeof(int), stream);

    deg_count<<<(NE + 255) / 256, 256, 0, stream>>>(dst, deg);
    norm_reserve<<<(NN + 255) / 256, 256, 0, stream>>>(deg, norm, start, cursor, gctr);
    fill_csr<<<(NE + 255) / 256, 256, 0, stream>>>(src, dst, cursor, col);
    make_m<<<(2 * NC * NF + 255) / 256, 256, 0, stream>>>(Wsgc, Wlin, Wproj, M);
    spmm<<<(NN * 8 + 255) / 256, 256, 0, stream>>>(feat, h1, norm, start, deg, col);
    spmm<<<(NN * 8 + 255) / 256, 256, 0, stream>>>(h1, h2, norm, start, deg, col);
    final_gemm<<<(NN + 255) / 256, 256, 0, stream>>>(feat, h2, M, out);
}

// Round 4
// 307.373 us; speedup vs baseline: 1.0086x; 1.0086x over previous
//
#include <hip/hip_runtime.h>
#include <hip/hip_bf16.h>

#define NN 50000
#define NE 800000
#define NF 96
#define NH 128
#define NC 40

// ---------------- workspace layout (bytes) ----------------
// deg    : int[NN]        @ 0
// start  : int[NN]        @ 200192
// cursor : int[NN]        @ 400384
// norm   : float[NN]      @ 600576
// gctr   : int[1]         @ 800768
// M      : float[2*40*96] @ 801280   (M1 then M2, row-major [m][c][j])
// col    : int[NE]        @ 832000
// h1     : float[NN*NF]   @ 4032000
// h2     : float[NN*NF]   @ 23232000
// total  : 42,432,000 bytes

__global__ void deg_count(const int* __restrict__ dst, int* __restrict__ deg) {
    int e = blockIdx.x * blockDim.x + threadIdx.x;
    if (e < NE) atomicAdd(&deg[dst[e]], 1);
}

// norm + unordered-CSR slab reservation (wave-aggregated atomic)
__global__ void norm_reserve(const int* __restrict__ deg, float* __restrict__ norm,
                             int* __restrict__ start, int* __restrict__ cursor,
                             int* __restrict__ gctr) {
    int v = blockIdx.x * blockDim.x + threadIdx.x;
    int d = (v < NN) ? deg[v] : 0;
    if (v < NN) norm[v] = (d > 0) ? (1.0f / sqrtf((float)d)) : 1.0f;
    // wave-64 inclusive scan of d
    int lane = threadIdx.x & 63;
    int incl = d;
    #pragma unroll
    for (int off = 1; off < 64; off <<= 1) {
        int n = __shfl_up(incl, off);
        if (lane >= off) incl += n;
    }
    int total = __shfl(incl, 63);
    int base = 0;
    if (lane == 63) base = atomicAdd(gctr, total);
    base = __shfl(base, 63);
    int st = base + incl - d;   // exclusive prefix + slab base
    if (v < NN) { start[v] = st; cursor[v] = st; }
}

__global__ void fill_csr(const int* __restrict__ src, const int* __restrict__ dst,
                         int* __restrict__ cursor, int* __restrict__ col) {
    int e = blockIdx.x * blockDim.x + threadIdx.x;
    if (e < NE) {
        int p = atomicAdd(&cursor[dst[e]], 1);
        col[p] = src[e];
    }
}

// M1[c][j] = sum_k Wproj[c][k]     * Wlin[k][j]
// M2[c][j] = sum_k Wproj[c][128+k] * Wsgc[k][j]
__global__ void make_m(const float* __restrict__ Wsgc, const float* __restrict__ Wlin,
                       const float* __restrict__ Wproj, float* __restrict__ M) {
    int t = blockIdx.x * blockDim.x + threadIdx.x;
    if (t >= 2 * NC * NF) return;
    int m = t / (NC * NF);
    int r = t % (NC * NF);
    int c = r / NF, j = r % NF;
    const float* A  = m ? Wsgc : Wlin;
    const float* wp = Wproj + c * (2 * NH) + m * NH;
    float acc = 0.f;
    #pragma unroll 4
    for (int k = 0; k < NH; ++k) acc = fmaf(wp[k], A[k * NF + j], acc);
    M[t] = acc;
}

// out[v] = norm[v] * sum_{p in row v} norm[col[p]] * in[col[p]]
// 8 lanes cooperate per node: lane L owns float4 slots {L, L+8, L+16}.
// 4-edge unroll: 4 col + 4 norm loads batched, then 12 independent float4
// row loads in flight, then FMAs applied in strict p-order (bitwise-identical
// accumulation vs the non-unrolled version).
__global__ __launch_bounds__(256) void spmm(const float* __restrict__ hin,
                                            float* __restrict__ hout,
                                            const float* __restrict__ norm,
                                            const int* __restrict__ start,
                                            const int* __restrict__ deg,
                                            const int* __restrict__ col) {
    int t = blockIdx.x * blockDim.x + threadIdx.x;
    int v = t >> 3;
    int lane = t & 7;
    if (v >= NN) return;
    float4 a0 = make_float4(0.f, 0.f, 0.f, 0.f);
    float4 a1 = a0, a2 = a0;
    int p0 = start[v], d = deg[v];
    int pend = p0 + d;
    const float4* base = (const float4*)hin;

    int p = p0;
    for (; p + 4 <= pend; p += 4) {
        int s0 = col[p], s1 = col[p + 1], s2 = col[p + 2], s3 = col[p + 3];
        float w0 = norm[s0], w1 = norm[s1], w2 = norm[s2], w3 = norm[s3];
        const float4* r0p = base + (size_t)s0 * (NF / 4);
        const float4* r1p = base + (size_t)s1 * (NF / 4);
        const float4* r2p = base + (size_t)s2 * (NF / 4);
        const float4* r3p = base + (size_t)s3 * (NF / 4);
        float4 x00 = r0p[lane], x01 = r0p[lane + 8], x02 = r0p[lane + 16];
        float4 x10 = r1p[lane], x11 = r1p[lane + 8], x12 = r1p[lane + 16];
        float4 x20 = r2p[lane], x21 = r2p[lane + 8], x22 = r2p[lane + 16];
        float4 x30 = r3p[lane], x31 = r3p[lane + 8], x32 = r3p[lane + 16];
        // edge 0
        a0.x = fmaf(w0, x00.x, a0.x); a0.y = fmaf(w0, x00.y, a0.y);
        a0.z = fmaf(w0, x00.z, a0.z); a0.w = fmaf(w0, x00.w, a0.w);
        a1.x = fmaf(w0, x01.x, a1.x); a1.y = fmaf(w0, x01.y, a1.y);
        a1.z = fmaf(w0, x01.z, a1.z); a1.w = fmaf(w0, x01.w, a1.w);
        a2.x = fmaf(w0, x02.x, a2.x); a2.y = fmaf(w0, x02.y, a2.y);
        a2.z = fmaf(w0, x02.z, a2.z); a2.w = fmaf(w0, x02.w, a2.w);
        // edge 1
        a0.x = fmaf(w1, x10.x, a0.x); a0.y = fmaf(w1, x10.y, a0.y);
        a0.z = fmaf(w1, x10.z, a0.z); a0.w = fmaf(w1, x10.w, a0.w);
        a1.x = fmaf(w1, x11.x, a1.x); a1.y = fmaf(w1, x11.y, a1.y);
        a1.z = fmaf(w1, x11.z, a1.z); a1.w = fmaf(w1, x11.w, a1.w);
        a2.x = fmaf(w1, x12.x, a2.x); a2.y = fmaf(w1, x12.y, a2.y);
        a2.z = fmaf(w1, x12.z, a2.z); a2.w = fmaf(w1, x12.w, a2.w);
        // edge 2
        a0.x = fmaf(w2, x20.x, a0.x); a0.y = fmaf(w2, x20.y, a0.y);
        a0.z = fmaf(w2, x20.z, a0.z); a0.w = fmaf(w2, x20.w, a0.w);
        a1.x = fmaf(w2, x21.x, a1.x); a1.y = fmaf(w2, x21.y, a1.y);
        a1.z = fmaf(w2, x21.z, a1.z); a1.w = fmaf(w2, x21.w, a1.w);
        a2.x = fmaf(w2, x22.x, a2.x); a2.y = fmaf(w2, x22.y, a2.y);
        a2.z = fmaf(w2, x22.z, a2.z); a2.w = fmaf(w2, x22.w, a2.w);
        // edge 3
        a0.x = fmaf(w3, x30.x, a0.x); a0.y = fmaf(w3, x30.y, a0.y);
        a0.z = fmaf(w3, x30.z, a0.z); a0.w = fmaf(w3, x30.w, a0.w);
        a1.x = fmaf(w3, x31.x, a1.x); a1.y = fmaf(w3, x31.y, a1.y);
        a1.z = fmaf(w3, x31.z, a1.z); a1.w = fmaf(w3, x31.w, a1.w);
        a2.x = fmaf(w3, x32.x, a2.x); a2.y = fmaf(w3, x32.y, a2.y);
        a2.z = fmaf(w3, x32.z, a2.z); a2.w = fmaf(w3, x32.w, a2.w);
    }
    for (; p < pend; ++p) {
        int s = col[p];
        float w = norm[s];
        const float4* row = base + (size_t)s * (NF / 4);
        float4 r0 = row[lane];
        float4 r1 = row[lane + 8];
        float4 r2 = row[lane + 16];
        a0.x = fmaf(w, r0.x, a0.x); a0.y = fmaf(w, r0.y, a0.y);
        a0.z = fmaf(w, r0.z, a0.z); a0.w = fmaf(w, r0.w, a0.w);
        a1.x = fmaf(w, r1.x, a1.x); a1.y = fmaf(w, r1.y, a1.y);
        a1.z = fmaf(w, r1.z, a1.z); a1.w = fmaf(w, r1.w, a1.w);
        a2.x = fmaf(w, r2.x, a2.x); a2.y = fmaf(w, r2.y, a2.y);
        a2.z = fmaf(w, r2.z, a2.z); a2.w = fmaf(w, r2.w, a2.w);
    }
    float nv = norm[v];
    float4* orow = (float4*)hout + (size_t)v * (NF / 4);
    orow[lane]      = make_float4(nv * a0.x, nv * a0.y, nv * a0.z, nv * a0.w);
    orow[lane + 8]  = make_float4(nv * a1.x, nv * a1.y, nv * a1.z, nv * a1.w);
    orow[lane + 16] = make_float4(nv * a2.x, nv * a2.y, nv * a2.z, nv * a2.w);
}

// out[v][c] = dot(f[v], M1[c]) + dot(h2[v], M2[c])
__global__ __launch_bounds__(256) void final_gemm(const float* __restrict__ f,
                                                  const float* __restrict__ h2,
                                                  const float* __restrict__ M,
                                                  float* __restrict__ out) {
    __shared__ float Ml[2 * NC * NF];
    for (int i = threadIdx.x; i < 2 * NC * NF; i += 256) Ml[i] = M[i];
    __syncthreads();

    int part = threadIdx.x & 3;
    int grp  = threadIdx.x >> 2;
    int vb = blockIdx.x * 256 + grp * 4;

    float acc[4][10];
    #pragma unroll
    for (int n = 0; n < 4; ++n)
        #pragma unroll
        for (int c = 0; c < 10; ++c) acc[n][c] = 0.f;

    const float4* M1 = (const float4*)(Ml);            // [40][24]
    const float4* M2 = (const float4*)(Ml + NC * NF);  // [40][24]
    int c0 = part * 10;

    for (int j4 = 0; j4 < NF / 4; ++j4) {
        float4 fr[4], hr[4];
        #pragma unroll
        for (int n = 0; n < 4; ++n) {
            int v = vb + n;
            if (v < NN) {
                fr[n] = ((const float4*)(f  + (size_t)v * NF))[j4];
                hr[n] = ((const float4*)(h2 + (size_t)v * NF))[j4];
            } else {
                fr[n] = make_float4(0.f, 0.f, 0.f, 0.f);
                hr[n] = make_float4(0.f, 0.f, 0.f, 0.f);
            }
        }
        #pragma unroll
        for (int cc = 0; cc < 10; ++cc) {
            float4 a = M1[(c0 + cc) * (NF / 4) + j4];
            float4 b = M2[(c0 + cc) * (NF / 4) + j4];
            #pragma unroll
            for (int n = 0; n < 4; ++n) {
                float t = acc[n][cc];
                t = fmaf(fr[n].x, a.x, t);
                t = fmaf(fr[n].y, a.y, t);
                t = fmaf(fr[n].z, a.z, t);
                t = fmaf(fr[n].w, a.w, t);
                t = fmaf(hr[n].x, b.x, t);
                t = fmaf(hr[n].y, b.y, t);
                t = fmaf(hr[n].z, b.z, t);
                t = fmaf(hr[n].w, b.w, t);
                acc[n][cc] = t;
            }
        }
    }
    #pragma unroll
    for (int n = 0; n < 4; ++n) {
        int v = vb + n;
        if (v < NN) {
            #pragma unroll
            for (int cc = 0; cc < 10; ++cc)
                out[(size_t)v * NC + c0 + cc] = acc[n][cc];
        }
    }
}

extern "C" void kernel_launch(void* const* d_in, const int* in_sizes, int n_in,
                              void* d_out, int out_size, void* d_ws, size_t ws_size,
                              hipStream_t stream) {
    const float* feat  = (const float*)d_in[0];
    const int*   src   = (const int*)d_in[1];
    const int*   dst   = (const int*)d_in[2];
    const float* Wsgc  = (const float*)d_in[3];
    const float* Wlin  = (const float*)d_in[4];
    const float* Wproj = (const float*)d_in[5];
    float* out = (float*)d_out;
    char* ws = (char*)d_ws;

    int*   deg    = (int*)(ws + 0);
    int*   start  = (int*)(ws + 200192);
    int*   cursor = (int*)(ws + 400384);
    float* norm   = (float*)(ws + 600576);
    int*   gctr   = (int*)(ws + 800768);
    float* M      = (float*)(ws + 801280);
    int*   col    = (int*)(ws + 832000);
    float* h1     = (float*)(ws + 4032000);
    float* h2     = (float*)(ws + 23232000);

    hipMemsetAsync(deg, 0, NN * sizeof(int), stream);
    hipMemsetAsync(gctr, 0, sizeof(int), stream);

    deg_count<<<(NE + 255) / 256, 256, 0, stream>>>(dst, deg);
    norm_reserve<<<(NN + 255) / 256, 256, 0, stream>>>(deg, norm, start, cursor, gctr);
    fill_csr<<<(NE + 255) / 256, 256, 0, stream>>>(src, dst, cursor, col);
    make_m<<<(2 * NC * NF + 255) / 256, 256, 0, stream>>>(Wsgc, Wlin, Wproj, M);
    spmm<<<(NN * 8 + 255) / 256, 256, 0, stream>>>(feat, h1, norm, start, deg, col);
    spmm<<<(NN * 8 + 255) / 256, 256, 0, stream>>>(h1, h2, norm, start, deg, col);
    final_gemm<<<(NN + 255) / 256, 256, 0, stream>>>(feat, h2, M, out);
}

// Round 7
// 284.735 us; speedup vs baseline: 1.0888x; 1.0795x over previous
//
#include <hip/hip_runtime.h>
#include <hip/hip_bf16.h>

#define NN 50000
#define NE 800000
#define NF 96
#define NH 128
#define NC 40

// ---------------- workspace layout (bytes) ----------------
// deg    : int[NN]        @ 0
// start  : int[NN]        @ 200192
// cursor : int[NN]        @ 400384
// norm   : float[NN]      @ 600576
// gctr   : int[1]         @ 800768
// M      : float[2*40*96] @ 801280   (M1 then M2, row-major [m][c][j])
// col    : int[NE]        @ 832000
// x1     : float[NN*NC]   @ 4032000   (= f @ M1^T)
// y      : float[NN*NC]   @ 12032000  (= f @ M2^T)
// z1     : float[NN*NC]   @ 20032000  (= Anorm y)
// total  : 28,032,000 bytes

__global__ void deg_count(const int* __restrict__ dst, int* __restrict__ deg) {
    int e = blockIdx.x * blockDim.x + threadIdx.x;
    if (e < NE) atomicAdd(&deg[dst[e]], 1);
}

// norm + unordered-CSR slab reservation (wave-aggregated atomic)
__global__ void norm_reserve(const int* __restrict__ deg, float* __restrict__ norm,
                             int* __restrict__ start, int* __restrict__ cursor,
                             int* __restrict__ gctr) {
    int v = blockIdx.x * blockDim.x + threadIdx.x;
    int d = (v < NN) ? deg[v] : 0;
    if (v < NN) norm[v] = (d > 0) ? (1.0f / sqrtf((float)d)) : 1.0f;
    int lane = threadIdx.x & 63;
    int incl = d;
    #pragma unroll
    for (int off = 1; off < 64; off <<= 1) {
        int n = __shfl_up(incl, off);
        if (lane >= off) incl += n;
    }
    int total = __shfl(incl, 63);
    int base = 0;
    if (lane == 63) base = atomicAdd(gctr, total);
    base = __shfl(base, 63);
    int st = base + incl - d;
    if (v < NN) { start[v] = st; cursor[v] = st; }
}

__global__ void fill_csr(const int* __restrict__ src, const int* __restrict__ dst,
                         int* __restrict__ cursor, int* __restrict__ col) {
    int e = blockIdx.x * blockDim.x + threadIdx.x;
    if (e < NE) {
        int p = atomicAdd(&cursor[dst[e]], 1);
        col[p] = src[e];
    }
}

// M1[c][j] = sum_k Wproj[c][k]     * Wlin[k][j]
// M2[c][j] = sum_k Wproj[c][128+k] * Wsgc[k][j]
__global__ void make_m(const float* __restrict__ Wsgc, const float* __restrict__ Wlin,
                       const float* __restrict__ Wproj, float* __restrict__ M) {
    int t = blockIdx.x * blockDim.x + threadIdx.x;
    if (t >= 2 * NC * NF) return;
    int m = t / (NC * NF);
    int r = t % (NC * NF);
    int c = r / NF, j = r % NF;
    const float* A  = m ? Wsgc : Wlin;
    const float* wp = Wproj + c * (2 * NH) + m * NH;
    float acc = 0.f;
    #pragma unroll 4
    for (int k = 0; k < NH; ++k) acc = fmaf(wp[k], A[k * NF + j], acc);
    M[t] = acc;
}

// One pass over f: x1[v][c] = dot(f[v], M1[c]), y[v][c] = dot(f[v], M2[c]).
// 256 thr: part=tid&3 (10 classes), grp=tid>>2 handles 2 nodes; block = 128 nodes.
__global__ __launch_bounds__(256) void proj(const float* __restrict__ f,
                                            const float* __restrict__ M,
                                            float* __restrict__ x1,
                                            float* __restrict__ y) {
    __shared__ float Ml[2 * NC * NF];
    for (int i = threadIdx.x; i < 2 * NC * NF; i += 256) Ml[i] = M[i];
    __syncthreads();

    int part = threadIdx.x & 3;
    int grp  = threadIdx.x >> 2;
    int vb = blockIdx.x * 128 + grp * 2;
    int c0 = part * 10;

    float acc1[2][10], acc2[2][10];
    #pragma unroll
    for (int n = 0; n < 2; ++n)
        #pragma unroll
        for (int c = 0; c < 10; ++c) { acc1[n][c] = 0.f; acc2[n][c] = 0.f; }

    const float4* M1 = (const float4*)(Ml);            // [40][24]
    const float4* M2 = (const float4*)(Ml + NC * NF);  // [40][24]

    for (int j4 = 0; j4 < NF / 4; ++j4) {
        float4 fr[2];
        #pragma unroll
        for (int n = 0; n < 2; ++n) {
            int v = vb + n;
            fr[n] = (v < NN) ? ((const float4*)(f + (size_t)v * NF))[j4]
                             : make_float4(0.f, 0.f, 0.f, 0.f);
        }
        #pragma unroll
        for (int cc = 0; cc < 10; ++cc) {
            float4 a = M1[(c0 + cc) * (NF / 4) + j4];
            float4 b = M2[(c0 + cc) * (NF / 4) + j4];
            #pragma unroll
            for (int n = 0; n < 2; ++n) {
                float t1 = acc1[n][cc];
                t1 = fmaf(fr[n].x, a.x, t1);
                t1 = fmaf(fr[n].y, a.y, t1);
                t1 = fmaf(fr[n].z, a.z, t1);
                t1 = fmaf(fr[n].w, a.w, t1);
                acc1[n][cc] = t1;
                float t2 = acc2[n][cc];
                t2 = fmaf(fr[n].x, b.x, t2);
                t2 = fmaf(fr[n].y, b.y, t2);
                t2 = fmaf(fr[n].z, b.z, t2);
                t2 = fmaf(fr[n].w, b.w, t2);
                acc2[n][cc] = t2;
            }
        }
    }
    #pragma unroll
    for (int n = 0; n < 2; ++n) {
        int v = vb + n;
        if (v < NN) {
            #pragma unroll
            for (int cc = 0; cc < 10; ++cc) {
                x1[(size_t)v * NC + c0 + cc] = acc1[n][cc];
                y [(size_t)v * NC + c0 + cc] = acc2[n][cc];
            }
        }
    }
}

// out[v] = norm[v]*sum_{p in row v} norm[col[p]]*yin[col[p]]  (+ addv[v] if FUSE)
// 8 lanes/node; row = 10 float4 (160B): lane L owns slot L; lanes 0,1 own 8+L.
template <int FUSE>
__global__ __launch_bounds__(256) void spmm40(const float* __restrict__ yin,
                                              float* __restrict__ yout,
                                              const float* __restrict__ addv,
                                              const float* __restrict__ norm,
                                              const int* __restrict__ start,
                                              const int* __restrict__ deg,
                                              const int* __restrict__ col) {
    int t = blockIdx.x * blockDim.x + threadIdx.x;
    int v = t >> 3;
    int lane = t & 7;
    if (v >= NN) return;
    const bool tl = (lane < 2);
    float4 a0 = make_float4(0.f, 0.f, 0.f, 0.f);
    float4 a1 = a0;
    int p0 = start[v], pend = p0 + deg[v];
    const float4* base = (const float4*)yin;
    const float4 zero = make_float4(0.f, 0.f, 0.f, 0.f);

    int p = p0;
    for (; p + 4 <= pend; p += 4) {
        int s0 = col[p], s1 = col[p + 1], s2 = col[p + 2], s3 = col[p + 3];
        float w0 = norm[s0], w1 = norm[s1], w2 = norm[s2], w3 = norm[s3];
        const float4* r0 = base + (size_t)s0 * (NC / 4);
        const float4* r1 = base + (size_t)s1 * (NC / 4);
        const float4* r2 = base + (size_t)s2 * (NC / 4);
        const float4* r3 = base + (size_t)s3 * (NC / 4);
        float4 x0 = r0[lane], x1_ = r1[lane], x2 = r2[lane], x3 = r3[lane];
        float4 y0 = tl ? r0[8 + lane] : zero;
        float4 y1 = tl ? r1[8 + lane] : zero;
        float4 y2 = tl ? r2[8 + lane] : zero;
        float4 y3 = tl ? r3[8 + lane] : zero;
        a0.x = fmaf(w0, x0.x, a0.x);  a0.y = fmaf(w0, x0.y, a0.y);
        a0.z = fmaf(w0, x0.z, a0.z);  a0.w = fmaf(w0, x0.w, a0.w);
        a1.x = fmaf(w0, y0.x, a1.x);  a1.y = fmaf(w0, y0.y, a1.y);
        a1.z = fmaf(w0, y0.z, a1.z);  a1.w = fmaf(w0, y0.w, a1.w);
        a0.x = fmaf(w1, x1_.x, a0.x); a0.y = fmaf(w1, x1_.y, a0.y);
        a0.z = fmaf(w1, x1_.z, a0.z); a0.w = fmaf(w1, x1_.w, a0.w);
        a1.x = fmaf(w1, y1.x, a1.x);  a1.y = fmaf(w1, y1.y, a1.y);
        a1.z = fmaf(w1, y1.z, a1.z);  a1.w = fmaf(w1, y1.w, a1.w);
        a0.x = fmaf(w2, x2.x, a0.x);  a0.y = fmaf(w2, x2.y, a0.y);
        a0.z = fmaf(w2, x2.z, a0.z);  a0.w = fmaf(w2, x2.w, a0.w);
        a1.x = fmaf(w2, y2.x, a1.x);  a1.y = fmaf(w2, y2.y, a1.y);
        a1.z = fmaf(w2, y2.z, a1.z);  a1.w = fmaf(w2, y2.w, a1.w);
        a0.x = fmaf(w3, x3.x, a0.x);  a0.y = fmaf(w3, x3.y, a0.y);
        a0.z = fmaf(w3, x3.z, a0.z);  a0.w = fmaf(w3, x3.w, a0.w);
        a1.x = fmaf(w3, y3.x, a1.x);  a1.y = fmaf(w3, y3.y, a1.y);
        a1.z = fmaf(w3, y3.z, a1.z);  a1.w = fmaf(w3, y3.w, a1.w);
    }
    for (; p < pend; ++p) {
        int s = col[p];
        float w = norm[s];
        const float4* r = base + (size_t)s * (NC / 4);
        float4 x = r[lane];
        float4 yv = tl ? r[8 + lane] : zero;
        a0.x = fmaf(w, x.x, a0.x);  a0.y = fmaf(w, x.y, a0.y);
        a0.z = fmaf(w, x.z, a0.z);  a0.w = fmaf(w, x.w, a0.w);
        a1.x = fmaf(w, yv.x, a1.x); a1.y = fmaf(w, yv.y, a1.y);
        a1.z = fmaf(w, yv.z, a1.z); a1.w = fmaf(w, yv.w, a1.w);
    }

    float nv = norm[v];
    float4* orow = (float4*)yout + (size_t)v * (NC / 4);
    if (FUSE) {
        const float4* ar = (const float4*)addv + (size_t)v * (NC / 4);
        float4 b0 = ar[lane];
        b0.x = fmaf(nv, a0.x, b0.x); b0.y = fmaf(nv, a0.y, b0.y);
        b0.z = fmaf(nv, a0.z, b0.z); b0.w = fmaf(nv, a0.w, b0.w);
        orow[lane] = b0;
        if (tl) {
            float4 b1 = ar[8 + lane];
            b1.x = fmaf(nv, a1.x, b1.x); b1.y = fmaf(nv, a1.y, b1.y);
            b1.z = fmaf(nv, a1.z, b1.z); b1.w = fmaf(nv, a1.w, b1.w);
            orow[8 + lane] = b1;
        }
    } else {
        orow[lane] = make_float4(nv * a0.x, nv * a0.y, nv * a0.z, nv * a0.w);
        if (tl) orow[8 + lane] = make_float4(nv * a1.x, nv * a1.y, nv * a1.z, nv * a1.w);
    }
}

extern "C" void kernel_launch(void* const* d_in, const int* in_sizes, int n_in,
                              void* d_out, int out_size, void* d_ws, size_t ws_size,
                              hipStream_t stream) {
    const float* feat  = (const float*)d_in[0];
    const int*   src   = (const int*)d_in[1];
    const int*   dst   = (const int*)d_in[2];
    const float* Wsgc  = (const float*)d_in[3];
    const float* Wlin  = (const float*)d_in[4];
    const float* Wproj = (const float*)d_in[5];
    float* out = (float*)d_out;
    char* ws = (char*)d_ws;

    int*   deg    = (int*)(ws + 0);
    int*   start  = (int*)(ws + 200192);
    int*   cursor = (int*)(ws + 400384);
    float* norm   = (float*)(ws + 600576);
    int*   gctr   = (int*)(ws + 800768);
    float* M      = (float*)(ws + 801280);
    int*   col    = (int*)(ws + 832000);
    float* x1     = (float*)(ws + 4032000);
    float* y      = (float*)(ws + 12032000);
    float* z1     = (float*)(ws + 20032000);

    hipMemsetAsync(deg, 0, NN * sizeof(int), stream);
    hipMemsetAsync(gctr, 0, sizeof(int), stream);

    deg_count<<<(NE + 255) / 256, 256, 0, stream>>>(dst, deg);
    norm_reserve<<<(NN + 255) / 256, 256, 0, stream>>>(deg, norm, start, cursor, gctr);
    fill_csr<<<(NE + 255) / 256, 256, 0, stream>>>(src, dst, cursor, col);
    make_m<<<(2 * NC * NF + 255) / 256, 256, 0, stream>>>(Wsgc, Wlin, Wproj, M);
    proj<<<(NN + 127) / 128, 256, 0, stream>>>(feat, M, x1, y);
    spmm40<0><<<(NN * 8 + 255) / 256, 256, 0, stream>>>(y, z1, nullptr, norm, start, deg, col);
    spmm40<1><<<(NN * 8 + 255) / 256, 256, 0, stream>>>(z1, out, x1, norm, start, deg, col);
}

// Round 10
// 225.473 us; speedup vs baseline: 1.3750x; 1.2628x over previous
//
#include <hip/hip_runtime.h>
#include <hip/hip_bf16.h>

#define NN 50000
#define NE 800000
#define NF 96
#define NH 128
#define NC 40

#define BKLOG 8                 // 256 nodes per bucket
#define NB 196                  // ceil(NN/256)
#define EPB 4096                // edges per block in hist/partition
#define NBLK 196                // ceil(NE/EPB)
#define CAP 6144                // col staging capacity per bucket (mean 4096, +32 sigma)

// ---------------- workspace layout (bytes) ----------------
// deg   : int[NN]      @ 0
// start : int[NN]      @ 200192
// norm  : float[NN]    @ 400384
// bcnt  : int[NB]      @ 600576
// boff  : int[NB+1]    @ 601600
// bcur  : int[NB]      @ 602624
// M     : float[7680]  @ 603648   (M1 then M2, row-major [m][c][j])
// col   : int[NE]      @ 634368
// pairs : uint[NE]     @ 3834368  (src | local_dst<<16)
// x1    : float[NN*NC] @ 7034368   (= f @ M1^T)
// y     : float[NN*NC] @ 15034368  (= f @ M2^T)
// z1    : float[NN*NC] @ 23034368  (= Anorm y)
// total : 31,034,368 bytes

// ---- pass 1: per-bucket edge histogram (LDS-staged) ----
__global__ __launch_bounds__(256) void edge_hist(const int* __restrict__ dst,
                                                 int* __restrict__ bcnt) {
    __shared__ int h[NB];
    int tid = threadIdx.x;
    for (int i = tid; i < NB; i += 256) h[i] = 0;
    __syncthreads();
    int e0 = blockIdx.x * EPB;
    #pragma unroll
    for (int k = 0; k < 16; ++k) {
        int e = e0 + k * 256 + tid;
        if (e < NE) atomicAdd(&h[dst[e] >> BKLOG], 1);
    }
    __syncthreads();
    for (int i = tid; i < NB; i += 256) {
        int c = h[i];
        if (c) atomicAdd(&bcnt[i], c);
    }
}

// ---- pass 2: exclusive scan of bucket counts (single block) ----
__global__ __launch_bounds__(256) void scan_buckets(const int* __restrict__ bcnt,
                                                    int* __restrict__ boff,
                                                    int* __restrict__ bcur) {
    int t = threadIdx.x;
    int v = (t < NB) ? bcnt[t] : 0;
    int lane = t & 63, w = t >> 6;
    int incl = v;
    #pragma unroll
    for (int off = 1; off < 64; off <<= 1) {
        int n = __shfl_up(incl, off);
        if (lane >= off) incl += n;
    }
    __shared__ int ws[4];
    if (lane == 63) ws[w] = incl;
    __syncthreads();
    int add = 0;
    for (int i = 0; i < w; ++i) add += ws[i];
    incl += add;
    int excl = incl - v;
    if (t < NB) { boff[t] = excl; bcur[t] = excl; }
    if (t == 255) boff[NB] = incl;   // = NE
}

// ---- pass 3: LDS-staged partition of packed edges into bucket slabs ----
__global__ __launch_bounds__(256) void partition(const int* __restrict__ src,
                                                 const int* __restrict__ dst,
                                                 int* __restrict__ bcur,
                                                 unsigned* __restrict__ pairs) {
    __shared__ int h[NB];
    __shared__ int loff[NB];
    __shared__ int gbase[NB];
    __shared__ int ws[4];
    __shared__ unsigned buf[EPB];
    __shared__ unsigned char slotbin[EPB];
    int tid = threadIdx.x;
    for (int i = tid; i < NB; i += 256) h[i] = 0;
    __syncthreads();
    int e0 = blockIdx.x * EPB;
    int myBin[16]; int myRank[16]; unsigned myVal[16];
    #pragma unroll
    for (int k = 0; k < 16; ++k) {
        int e = e0 + k * 256 + tid;
        if (e < NE) {
            int d = dst[e];
            int b = d >> BKLOG;
            myBin[k]  = b;
            myRank[k] = atomicAdd(&h[b], 1);
            myVal[k]  = (unsigned)src[e] | ((unsigned)(d & ((1 << BKLOG) - 1)) << 16);
        } else {
            myBin[k] = -1;
        }
    }
    __syncthreads();
    // scan local histogram, reserve global slabs
    {
        int v = (tid < NB) ? h[tid] : 0;
        int lane = tid & 63, w = tid >> 6;
        int incl = v;
        #pragma unroll
        for (int off = 1; off < 64; off <<= 1) {
            int n = __shfl_up(incl, off);
            if (lane >= off) incl += n;
        }
        if (lane == 63) ws[w] = incl;
        __syncthreads();
        int add = 0;
        for (int i = 0; i < w; ++i) add += ws[i];
        incl += add;
        if (tid < NB) {
            loff[tid]  = incl - v;
            gbase[tid] = (v > 0) ? atomicAdd(&bcur[tid], v) : 0;
        }
    }
    __syncthreads();
    // slot -> bin map (for coalesced copy-out)
    for (int b = tid; b < NB; b += 256) {
        int o = loff[b], c = h[b];
        for (int j = 0; j < c; ++j) slotbin[o + j] = (unsigned char)b;
    }
    // scatter values into LDS by (bin, rank)
    #pragma unroll
    for (int k = 0; k < 16; ++k) {
        if (myBin[k] >= 0) buf[loff[myBin[k]] + myRank[k]] = myVal[k];
    }
    __syncthreads();
    // copy out: piecewise-contiguous runs per bucket
    int nloc = (e0 + EPB <= NE) ? EPB : (NE - e0);
    for (int s = tid; s < nloc; s += 256) {
        int b = slotbin[s];
        pairs[gbase[b] + (s - loff[b])] = buf[s];
    }
}

// ---- pass 4: per-bucket CSR finalize: deg/start/norm + LDS-staged col ----
__global__ __launch_bounds__(256) void build_bucket(const unsigned* __restrict__ pairs,
                                                    const int* __restrict__ boff,
                                                    int* __restrict__ deg,
                                                    int* __restrict__ start,
                                                    float* __restrict__ norm,
                                                    int* __restrict__ col) {
    __shared__ int cnt[256];
    __shared__ int cur[256];
    __shared__ int ws[4];
    __shared__ unsigned colbuf[CAP];
    int tid = threadIdx.x;
    int b = blockIdx.x;
    int p0 = boff[b], p1 = boff[b + 1];
    int n = p1 - p0;
    cnt[tid] = 0;
    __syncthreads();
    for (int i = tid; i < n; i += 256) atomicAdd(&cnt[pairs[p0 + i] >> 16], 1);
    __syncthreads();
    int c = cnt[tid];
    int lane = tid & 63, w = tid >> 6;
    int incl = c;
    #pragma unroll
    for (int off = 1; off < 64; off <<= 1) {
        int x = __shfl_up(incl, off);
        if (lane >= off) incl += x;
    }
    if (lane == 63) ws[w] = incl;
    __syncthreads();
    int add = 0;
    for (int i = 0; i < w; ++i) add += ws[i];
    incl += add;
    int excl = incl - c;
    int v = (b << BKLOG) + tid;
    if (v < NN) {
        deg[v]   = c;
        start[v] = p0 + excl;
        norm[v]  = (c > 0) ? (1.0f / sqrtf((float)c)) : 1.0f;
    }
    cur[tid] = excl;
    __syncthreads();
    for (int i = tid; i < n; i += 256) {
        unsigned x = pairs[p0 + i];
        int lid = x >> 16;
        int pos = atomicAdd(&cur[lid], 1);
        unsigned s = x & 0xFFFFu;
        if (pos < CAP) colbuf[pos] = s;
        else           col[p0 + pos] = (int)s;
    }
    __syncthreads();
    int lim = (n < CAP) ? n : CAP;
    for (int i = tid; i < lim; i += 256) col[p0 + i] = (int)colbuf[i];
}

// M1[c][j] = sum_k Wproj[c][k]     * Wlin[k][j]
// M2[c][j] = sum_k Wproj[c][128+k] * Wsgc[k][j]
__global__ void make_m(const float* __restrict__ Wsgc, const float* __restrict__ Wlin,
                       const float* __restrict__ Wproj, float* __restrict__ M) {
    int t = blockIdx.x * blockDim.x + threadIdx.x;
    if (t >= 2 * NC * NF) return;
    int m = t / (NC * NF);
    int r = t % (NC * NF);
    int c = r / NF, j = r % NF;
    const float* A  = m ? Wsgc : Wlin;
    const float* wp = Wproj + c * (2 * NH) + m * NH;
    float acc = 0.f;
    #pragma unroll 4
    for (int k = 0; k < NH; ++k) acc = fmaf(wp[k], A[k * NF + j], acc);
    M[t] = acc;
}

// One pass over f: x1[v][c] = dot(f[v], M1[c]), y[v][c] = dot(f[v], M2[c]).
__global__ __launch_bounds__(256) void proj(const float* __restrict__ f,
                                            const float* __restrict__ M,
                                            float* __restrict__ x1,
                                            float* __restrict__ y) {
    __shared__ float Ml[2 * NC * NF];
    for (int i = threadIdx.x; i < 2 * NC * NF; i += 256) Ml[i] = M[i];
    __syncthreads();

    int part = threadIdx.x & 3;
    int grp  = threadIdx.x >> 2;
    int vb = blockIdx.x * 128 + grp * 2;
    int c0 = part * 10;

    float acc1[2][10], acc2[2][10];
    #pragma unroll
    for (int n = 0; n < 2; ++n)
        #pragma unroll
        for (int c = 0; c < 10; ++c) { acc1[n][c] = 0.f; acc2[n][c] = 0.f; }

    const float4* M1 = (const float4*)(Ml);            // [40][24]
    const float4* M2 = (const float4*)(Ml + NC * NF);  // [40][24]

    for (int j4 = 0; j4 < NF / 4; ++j4) {
        float4 fr[2];
        #pragma unroll
        for (int n = 0; n < 2; ++n) {
            int v = vb + n;
            fr[n] = (v < NN) ? ((const float4*)(f + (size_t)v * NF))[j4]
                             : make_float4(0.f, 0.f, 0.f, 0.f);
        }
        #pragma unroll
        for (int cc = 0; cc < 10; ++cc) {
            float4 a = M1[(c0 + cc) * (NF / 4) + j4];
            float4 b = M2[(c0 + cc) * (NF / 4) + j4];
            #pragma unroll
            for (int n = 0; n < 2; ++n) {
                float t1 = acc1[n][cc];
                t1 = fmaf(fr[n].x, a.x, t1);
                t1 = fmaf(fr[n].y, a.y, t1);
                t1 = fmaf(fr[n].z, a.z, t1);
                t1 = fmaf(fr[n].w, a.w, t1);
                acc1[n][cc] = t1;
                float t2 = acc2[n][cc];
                t2 = fmaf(fr[n].x, b.x, t2);
                t2 = fmaf(fr[n].y, b.y, t2);
                t2 = fmaf(fr[n].z, b.z, t2);
                t2 = fmaf(fr[n].w, b.w, t2);
                acc2[n][cc] = t2;
            }
        }
    }
    #pragma unroll
    for (int n = 0; n < 2; ++n) {
        int v = vb + n;
        if (v < NN) {
            #pragma unroll
            for (int cc = 0; cc < 10; ++cc) {
                x1[(size_t)v * NC + c0 + cc] = acc1[n][cc];
                y [(size_t)v * NC + c0 + cc] = acc2[n][cc];
            }
        }
    }
}

// out[v] = norm[v]*sum_{p in row v} norm[col[p]]*yin[col[p]]  (+ addv[v] if FUSE)
// 8 lanes/node; row = 10 float4 (160B): lane L owns slot L; lanes 0,1 own 8+L.
template <int FUSE>
__global__ __launch_bounds__(256) void spmm40(const float* __restrict__ yin,
                                              float* __restrict__ yout,
                                              const float* __restrict__ addv,
                                              const float* __restrict__ norm,
                                              const int* __restrict__ start,
                                              const int* __restrict__ deg,
                                              const int* __restrict__ col) {
    int t = blockIdx.x * blockDim.x + threadIdx.x;
    int v = t >> 3;
    int lane = t & 7;
    if (v >= NN) return;
    const bool tl = (lane < 2);
    float4 a0 = make_float4(0.f, 0.f, 0.f, 0.f);
    float4 a1 = a0;
    int p0 = start[v], pend = p0 + deg[v];
    const float4* base = (const float4*)yin;
    const float4 zero = make_float4(0.f, 0.f, 0.f, 0.f);

    int p = p0;
    for (; p + 4 <= pend; p += 4) {
        int s0 = col[p], s1 = col[p + 1], s2 = col[p + 2], s3 = col[p + 3];
        float w0 = norm[s0], w1 = norm[s1], w2 = norm[s2], w3 = norm[s3];
        const float4* r0 = base + (size_t)s0 * (NC / 4);
        const float4* r1 = base + (size_t)s1 * (NC / 4);
        const float4* r2 = base + (size_t)s2 * (NC / 4);
        const float4* r3 = base + (size_t)s3 * (NC / 4);
        float4 x0 = r0[lane], x1_ = r1[lane], x2 = r2[lane], x3 = r3[lane];
        float4 y0 = tl ? r0[8 + lane] : zero;
        float4 y1 = tl ? r1[8 + lane] : zero;
        float4 y2 = tl ? r2[8 + lane] : zero;
        float4 y3 = tl ? r3[8 + lane] : zero;
        a0.x = fmaf(w0, x0.x, a0.x);  a0.y = fmaf(w0, x0.y, a0.y);
        a0.z = fmaf(w0, x0.z, a0.z);  a0.w = fmaf(w0, x0.w, a0.w);
        a1.x = fmaf(w0, y0.x, a1.x);  a1.y = fmaf(w0, y0.y, a1.y);
        a1.z = fmaf(w0, y0.z, a1.z);  a1.w = fmaf(w0, y0.w, a1.w);
        a0.x = fmaf(w1, x1_.x, a0.x); a0.y = fmaf(w1, x1_.y, a0.y);
        a0.z = fmaf(w1, x1_.z, a0.z); a0.w = fmaf(w1, x1_.w, a0.w);
        a1.x = fmaf(w1, y1.x, a1.x);  a1.y = fmaf(w1, y1.y, a1.y);
        a1.z = fmaf(w1, y1.z, a1.z);  a1.w = fmaf(w1, y1.w, a1.w);
        a0.x = fmaf(w2, x2.x, a0.x);  a0.y = fmaf(w2, x2.y, a0.y);
        a0.z = fmaf(w2, x2.z, a0.z);  a0.w = fmaf(w2, x2.w, a0.w);
        a1.x = fmaf(w2, y2.x, a1.x);  a1.y = fmaf(w2, y2.y, a1.y);
        a1.z = fmaf(w2, y2.z, a1.z);  a1.w = fmaf(w2, y2.w, a1.w);
        a0.x = fmaf(w3, x3.x, a0.x);  a0.y = fmaf(w3, x3.y, a0.y);
        a0.z = fmaf(w3, x3.z, a0.z);  a0.w = fmaf(w3, x3.w, a0.w);
        a1.x = fmaf(w3, y3.x, a1.x);  a1.y = fmaf(w3, y3.y, a1.y);
        a1.z = fmaf(w3, y3.z, a1.z);  a1.w = fmaf(w3, y3.w, a1.w);
    }
    for (; p < pend; ++p) {
        int s = col[p];
        float w = norm[s];
        const float4* r = base + (size_t)s * (NC / 4);
        float4 x = r[lane];
        float4 yv = tl ? r[8 + lane] : zero;
        a0.x = fmaf(w, x.x, a0.x);  a0.y = fmaf(w, x.y, a0.y);
        a0.z = fmaf(w, x.z, a0.z);  a0.w = fmaf(w, x.w, a0.w);
        a1.x = fmaf(w, yv.x, a1.x); a1.y = fmaf(w, yv.y, a1.y);
        a1.z = fmaf(w, yv.z, a1.z); a1.w = fmaf(w, yv.w, a1.w);
    }

    float nv = norm[v];
    float4* orow = (float4*)yout + (size_t)v * (NC / 4);
    if (FUSE) {
        const float4* ar = (const float4*)addv + (size_t)v * (NC / 4);
        float4 b0 = ar[lane];
        b0.x = fmaf(nv, a0.x, b0.x); b0.y = fmaf(nv, a0.y, b0.y);
        b0.z = fmaf(nv, a0.z, b0.z); b0.w = fmaf(nv, a0.w, b0.w);
        orow[lane] = b0;
        if (tl) {
            float4 b1 = ar[8 + lane];
            b1.x = fmaf(nv, a1.x, b1.x); b1.y = fmaf(nv, a1.y, b1.y);
            b1.z = fmaf(nv, a1.z, b1.z); b1.w = fmaf(nv, a1.w, b1.w);
            orow[8 + lane] = b1;
        }
    } else {
        orow[lane] = make_float4(nv * a0.x, nv * a0.y, nv * a0.z, nv * a0.w);
        if (tl) orow[8 + lane] = make_float4(nv * a1.x, nv * a1.y, nv * a1.z, nv * a1.w);
    }
}

extern "C" void kernel_launch(void* const* d_in, const int* in_sizes, int n_in,
                              void* d_out, int out_size, void* d_ws, size_t ws_size,
                              hipStream_t stream) {
    const float* feat  = (const float*)d_in[0];
    const int*   src   = (const int*)d_in[1];
    const int*   dst   = (const int*)d_in[2];
    const float* Wsgc  = (const float*)d_in[3];
    const float* Wlin  = (const float*)d_in[4];
    const float* Wproj = (const float*)d_in[5];
    float* out = (float*)d_out;
    char* ws = (char*)d_ws;

    int*      deg   = (int*)(ws + 0);
    int*      start = (int*)(ws + 200192);
    float*    norm  = (float*)(ws + 400384);
    int*      bcnt  = (int*)(ws + 600576);
    int*      boff  = (int*)(ws + 601600);
    int*      bcur  = (int*)(ws + 602624);
    float*    M     = (float*)(ws + 603648);
    int*      col   = (int*)(ws + 634368);
    unsigned* pairs = (unsigned*)(ws + 3834368);
    float*    x1    = (float*)(ws + 7034368);
    float*    y     = (float*)(ws + 15034368);
    float*    z1    = (float*)(ws + 23034368);

    hipMemsetAsync(bcnt, 0, NB * sizeof(int), stream);

    edge_hist<<<NBLK, 256, 0, stream>>>(dst, bcnt);
    scan_buckets<<<1, 256, 0, stream>>>(bcnt, boff, bcur);
    partition<<<NBLK, 256, 0, stream>>>(src, dst, bcur, pairs);
    build_bucket<<<NB, 256, 0, stream>>>(pairs, boff, deg, start, norm, col);
    make_m<<<(2 * NC * NF + 255) / 256, 256, 0, stream>>>(Wsgc, Wlin, Wproj, M);
    proj<<<(NN + 127) / 128, 256, 0, stream>>>(feat, M, x1, y);
    spmm40<0><<<(NN * 8 + 255) / 256, 256, 0, stream>>>(y, z1, nullptr, norm, start, deg, col);
    spmm40<1><<<(NN * 8 + 255) / 256, 256, 0, stream>>>(z1, out, x1, norm, start, deg, col);
}

// Round 13
// 219.707 us; speedup vs baseline: 1.4111x; 1.0262x over previous
//
#include <hip/hip_runtime.h>
#include <hip/hip_bf16.h>

#define NN 50000
#define NE 800000
#define NF 96
#define NH 128
#define NC 40

#define BKLOG 8                 // 256 nodes per bucket
#define NB 196                  // ceil(NN/256)
#define EPB 4096                // edges per block in hist/partition
#define NBLK 196                // ceil(NE/EPB)
#define CAP 6144                // col staging capacity per bucket (mean 4096, +32 sigma)

// ---------------- workspace layout (bytes) ----------------
// deg   : int[NN]      @ 0
// start : int[NN]      @ 200192
// norm  : float[NN]    @ 400384
// bcnt  : int[NB]      @ 600576
// boff  : int[NB+1]    @ 601600
// bcur  : int[NB]      @ 602624
// M     : float[7680]  @ 603648   (M1 then M2, row-major [m][c][j])
// col   : int[NE]      @ 634368
// pairs : uint[NE]     @ 3834368  (src | local_dst<<16)
// x1    : float[NN*NC] @ 7034368   (= f @ M1^T)
// y     : float[NN*NC] @ 15034368  (= norm .* (f @ M2^T))
// z1    : float[NN*NC] @ 23034368  (= norm^2 .* (Ahat y))
// total : 31,034,368 bytes

// ---- pass 1: per-bucket edge histogram (LDS-staged) ----
__global__ __launch_bounds__(256) void edge_hist(const int* __restrict__ dst,
                                                 int* __restrict__ bcnt) {
    __shared__ int h[NB];
    int tid = threadIdx.x;
    for (int i = tid; i < NB; i += 256) h[i] = 0;
    __syncthreads();
    int e0 = blockIdx.x * EPB;
    #pragma unroll
    for (int k = 0; k < 16; ++k) {
        int e = e0 + k * 256 + tid;
        if (e < NE) atomicAdd(&h[dst[e] >> BKLOG], 1);
    }
    __syncthreads();
    for (int i = tid; i < NB; i += 256) {
        int c = h[i];
        if (c) atomicAdd(&bcnt[i], c);
    }
}

// ---- pass 2: exclusive scan of bucket counts (single block) ----
__global__ __launch_bounds__(256) void scan_buckets(const int* __restrict__ bcnt,
                                                    int* __restrict__ boff,
                                                    int* __restrict__ bcur) {
    int t = threadIdx.x;
    int v = (t < NB) ? bcnt[t] : 0;
    int lane = t & 63, w = t >> 6;
    int incl = v;
    #pragma unroll
    for (int off = 1; off < 64; off <<= 1) {
        int n = __shfl_up(incl, off);
        if (lane >= off) incl += n;
    }
    __shared__ int ws[4];
    if (lane == 63) ws[w] = incl;
    __syncthreads();
    int add = 0;
    for (int i = 0; i < w; ++i) add += ws[i];
    incl += add;
    int excl = incl - v;
    if (t < NB) { boff[t] = excl; bcur[t] = excl; }
    if (t == 255) boff[NB] = incl;   // = NE
}

// ---- pass 3: LDS-staged partition of packed edges into bucket slabs ----
__global__ __launch_bounds__(256) void partition(const int* __restrict__ src,
                                                 const int* __restrict__ dst,
                                                 int* __restrict__ bcur,
                                                 unsigned* __restrict__ pairs) {
    __shared__ int h[NB];
    __shared__ int loff[NB];
    __shared__ int gbase[NB];
    __shared__ int ws[4];
    __shared__ unsigned buf[EPB];
    __shared__ unsigned char slotbin[EPB];
    int tid = threadIdx.x;
    for (int i = tid; i < NB; i += 256) h[i] = 0;
    __syncthreads();
    int e0 = blockIdx.x * EPB;
    int myBin[16]; int myRank[16]; unsigned myVal[16];
    #pragma unroll
    for (int k = 0; k < 16; ++k) {
        int e = e0 + k * 256 + tid;
        if (e < NE) {
            int d = dst[e];
            int b = d >> BKLOG;
            myBin[k]  = b;
            myRank[k] = atomicAdd(&h[b], 1);
            myVal[k]  = (unsigned)src[e] | ((unsigned)(d & ((1 << BKLOG) - 1)) << 16);
        } else {
            myBin[k] = -1;
        }
    }
    __syncthreads();
    // scan local histogram, reserve global slabs
    {
        int v = (tid < NB) ? h[tid] : 0;
        int lane = tid & 63, w = tid >> 6;
        int incl = v;
        #pragma unroll
        for (int off = 1; off < 64; off <<= 1) {
            int n = __shfl_up(incl, off);
            if (lane >= off) incl += n;
        }
        if (lane == 63) ws[w] = incl;
        __syncthreads();
        int add = 0;
        for (int i = 0; i < w; ++i) add += ws[i];
        incl += add;
        if (tid < NB) {
            loff[tid]  = incl - v;
            gbase[tid] = (v > 0) ? atomicAdd(&bcur[tid], v) : 0;
        }
    }
    __syncthreads();
    // slot -> bin map (for coalesced copy-out)
    for (int b = tid; b < NB; b += 256) {
        int o = loff[b], c = h[b];
        for (int j = 0; j < c; ++j) slotbin[o + j] = (unsigned char)b;
    }
    // scatter values into LDS by (bin, rank)
    #pragma unroll
    for (int k = 0; k < 16; ++k) {
        if (myBin[k] >= 0) buf[loff[myBin[k]] + myRank[k]] = myVal[k];
    }
    __syncthreads();
    // copy out: piecewise-contiguous runs per bucket
    int nloc = (e0 + EPB <= NE) ? EPB : (NE - e0);
    for (int s = tid; s < nloc; s += 256) {
        int b = slotbin[s];
        pairs[gbase[b] + (s - loff[b])] = buf[s];
    }
}

// ---- pass 4: per-bucket CSR finalize: deg/start/norm + LDS-staged col ----
__global__ __launch_bounds__(256) void build_bucket(const unsigned* __restrict__ pairs,
                                                    const int* __restrict__ boff,
                                                    int* __restrict__ deg,
                                                    int* __restrict__ start,
                                                    float* __restrict__ norm,
                                                    int* __restrict__ col) {
    __shared__ int cnt[256];
    __shared__ int cur[256];
    __shared__ int ws[4];
    __shared__ unsigned colbuf[CAP];
    int tid = threadIdx.x;
    int b = blockIdx.x;
    int p0 = boff[b], p1 = boff[b + 1];
    int n = p1 - p0;
    cnt[tid] = 0;
    __syncthreads();
    for (int i = tid; i < n; i += 256) atomicAdd(&cnt[pairs[p0 + i] >> 16], 1);
    __syncthreads();
    int c = cnt[tid];
    int lane = tid & 63, w = tid >> 6;
    int incl = c;
    #pragma unroll
    for (int off = 1; off < 64; off <<= 1) {
        int x = __shfl_up(incl, off);
        if (lane >= off) incl += x;
    }
    if (lane == 63) ws[w] = incl;
    __syncthreads();
    int add = 0;
    for (int i = 0; i < w; ++i) add += ws[i];
    incl += add;
    int excl = incl - c;
    int v = (b << BKLOG) + tid;
    if (v < NN) {
        deg[v]   = c;
        start[v] = p0 + excl;
        norm[v]  = (c > 0) ? (1.0f / sqrtf((float)c)) : 1.0f;
    }
    cur[tid] = excl;
    __syncthreads();
    for (int i = tid; i < n; i += 256) {
        unsigned x = pairs[p0 + i];
        int lid = x >> 16;
        int pos = atomicAdd(&cur[lid], 1);
        unsigned s = x & 0xFFFFu;
        if (pos < CAP) colbuf[pos] = s;
        else           col[p0 + pos] = (int)s;
    }
    __syncthreads();
    int lim = (n < CAP) ? n : CAP;
    for (int i = tid; i < lim; i += 256) col[p0 + i] = (int)colbuf[i];
}

// M1[c][j] = sum_k Wproj[c][k]     * Wlin[k][j]
// M2[c][j] = sum_k Wproj[c][128+k] * Wsgc[k][j]
__global__ void make_m(const float* __restrict__ Wsgc, const float* __restrict__ Wlin,
                       const float* __restrict__ Wproj, float* __restrict__ M) {
    int t = blockIdx.x * blockDim.x + threadIdx.x;
    if (t >= 2 * NC * NF) return;
    int m = t / (NC * NF);
    int r = t % (NC * NF);
    int c = r / NF, j = r % NF;
    const float* A  = m ? Wsgc : Wlin;
    const float* wp = Wproj + c * (2 * NH) + m * NH;
    float acc = 0.f;
    #pragma unroll 4
    for (int k = 0; k < NH; ++k) acc = fmaf(wp[k], A[k * NF + j], acc);
    M[t] = acc;
}

// One pass over f: x1[v][c] = dot(f[v], M1[c]); y[v][c] = norm[v]*dot(f[v], M2[c]).
__global__ __launch_bounds__(256) void proj(const float* __restrict__ f,
                                            const float* __restrict__ M,
                                            const float* __restrict__ norm,
                                            float* __restrict__ x1,
                                            float* __restrict__ y) {
    __shared__ float Ml[2 * NC * NF];
    for (int i = threadIdx.x; i < 2 * NC * NF; i += 256) Ml[i] = M[i];
    __syncthreads();

    int part = threadIdx.x & 3;
    int grp  = threadIdx.x >> 2;
    int vb = blockIdx.x * 128 + grp * 2;
    int c0 = part * 10;

    float acc1[2][10], acc2[2][10];
    #pragma unroll
    for (int n = 0; n < 2; ++n)
        #pragma unroll
        for (int c = 0; c < 10; ++c) { acc1[n][c] = 0.f; acc2[n][c] = 0.f; }

    const float4* M1 = (const float4*)(Ml);            // [40][24]
    const float4* M2 = (const float4*)(Ml + NC * NF);  // [40][24]

    for (int j4 = 0; j4 < NF / 4; ++j4) {
        float4 fr[2];
        #pragma unroll
        for (int n = 0; n < 2; ++n) {
            int v = vb + n;
            fr[n] = (v < NN) ? ((const float4*)(f + (size_t)v * NF))[j4]
                             : make_float4(0.f, 0.f, 0.f, 0.f);
        }
        #pragma unroll
        for (int cc = 0; cc < 10; ++cc) {
            float4 a = M1[(c0 + cc) * (NF / 4) + j4];
            float4 b = M2[(c0 + cc) * (NF / 4) + j4];
            #pragma unroll
            for (int n = 0; n < 2; ++n) {
                float t1 = acc1[n][cc];
                t1 = fmaf(fr[n].x, a.x, t1);
                t1 = fmaf(fr[n].y, a.y, t1);
                t1 = fmaf(fr[n].z, a.z, t1);
                t1 = fmaf(fr[n].w, a.w, t1);
                acc1[n][cc] = t1;
                float t2 = acc2[n][cc];
                t2 = fmaf(fr[n].x, b.x, t2);
                t2 = fmaf(fr[n].y, b.y, t2);
                t2 = fmaf(fr[n].z, b.z, t2);
                t2 = fmaf(fr[n].w, b.w, t2);
                acc2[n][cc] = t2;
            }
        }
    }
    #pragma unroll
    for (int n = 0; n < 2; ++n) {
        int v = vb + n;
        if (v < NN) {
            float nv = norm[v];
            #pragma unroll
            for (int cc = 0; cc < 10; ++cc) {
                x1[(size_t)v * NC + c0 + cc] = acc1[n][cc];
                y [(size_t)v * NC + c0 + cc] = nv * acc2[n][cc];
            }
        }
    }
}

// Pure neighbor-sum SpMM (norm factored out of the loop):
//  MODE 0: out[v] = norm[v]^2 * sum_{p in row v} yin[col[p]]
//  MODE 1: out[v] = addv[v] + norm[v] * sum_{p in row v} yin[col[p]]
// 8 lanes/node; row = 10 float4 (160B): lane L owns slot L; lanes 0,1 own 8+L.
template <int MODE>
__global__ __launch_bounds__(256) void spmm_sum(const float* __restrict__ yin,
                                                float* __restrict__ yout,
                                                const float* __restrict__ addv,
                                                const float* __restrict__ norm,
                                                const int* __restrict__ start,
                                                const int* __restrict__ deg,
                                                const int* __restrict__ col) {
    int t = blockIdx.x * blockDim.x + threadIdx.x;
    int v = t >> 3;
    int lane = t & 7;
    if (v >= NN) return;
    const bool tl = (lane < 2);
    float4 a0 = make_float4(0.f, 0.f, 0.f, 0.f);
    float4 a1 = a0;
    int p0 = start[v], pend = p0 + deg[v];
    const float4* base = (const float4*)yin;
    const float4 zero = make_float4(0.f, 0.f, 0.f, 0.f);

    int p = p0;
    for (; p + 4 <= pend; p += 4) {
        int s0 = col[p], s1 = col[p + 1], s2 = col[p + 2], s3 = col[p + 3];
        const float4* r0 = base + (size_t)s0 * (NC / 4);
        const float4* r1 = base + (size_t)s1 * (NC / 4);
        const float4* r2 = base + (size_t)s2 * (NC / 4);
        const float4* r3 = base + (size_t)s3 * (NC / 4);
        float4 x0 = r0[lane], x1_ = r1[lane], x2 = r2[lane], x3 = r3[lane];
        float4 y0 = tl ? r0[8 + lane] : zero;
        float4 y1 = tl ? r1[8 + lane] : zero;
        float4 y2 = tl ? r2[8 + lane] : zero;
        float4 y3 = tl ? r3[8 + lane] : zero;
        a0.x += x0.x;  a0.y += x0.y;  a0.z += x0.z;  a0.w += x0.w;
        a1.x += y0.x;  a1.y += y0.y;  a1.z += y0.z;  a1.w += y0.w;
        a0.x += x1_.x; a0.y += x1_.y; a0.z += x1_.z; a0.w += x1_.w;
        a1.x += y1.x;  a1.y += y1.y;  a1.z += y1.z;  a1.w += y1.w;
        a0.x += x2.x;  a0.y += x2.y;  a0.z += x2.z;  a0.w += x2.w;
        a1.x += y2.x;  a1.y += y2.y;  a1.z += y2.z;  a1.w += y2.w;
        a0.x += x3.x;  a0.y += x3.y;  a0.z += x3.z;  a0.w += x3.w;
        a1.x += y3.x;  a1.y += y3.y;  a1.z += y3.z;  a1.w += y3.w;
    }
    for (; p < pend; ++p) {
        int s = col[p];
        const float4* r = base + (size_t)s * (NC / 4);
        float4 x = r[lane];
        float4 yv = tl ? r[8 + lane] : zero;
        a0.x += x.x;  a0.y += x.y;  a0.z += x.z;  a0.w += x.w;
        a1.x += yv.x; a1.y += yv.y; a1.z += yv.z; a1.w += yv.w;
    }

    float nv = norm[v];
    float s = (MODE == 0) ? (nv * nv) : nv;
    float4* orow = (float4*)yout + (size_t)v * (NC / 4);
    if (MODE == 1) {
        const float4* ar = (const float4*)addv + (size_t)v * (NC / 4);
        float4 b0 = ar[lane];
        b0.x = fmaf(s, a0.x, b0.x); b0.y = fmaf(s, a0.y, b0.y);
        b0.z = fmaf(s, a0.z, b0.z); b0.w = fmaf(s, a0.w, b0.w);
        orow[lane] = b0;
        if (tl) {
            float4 b1 = ar[8 + lane];
            b1.x = fmaf(s, a1.x, b1.x); b1.y = fmaf(s, a1.y, b1.y);
            b1.z = fmaf(s, a1.z, b1.z); b1.w = fmaf(s, a1.w, b1.w);
            orow[8 + lane] = b1;
        }
    } else {
        orow[lane] = make_float4(s * a0.x, s * a0.y, s * a0.z, s * a0.w);
        if (tl) orow[8 + lane] = make_float4(s * a1.x, s * a1.y, s * a1.z, s * a1.w);
    }
}

extern "C" void kernel_launch(void* const* d_in, const int* in_sizes, int n_in,
                              void* d_out, int out_size, void* d_ws, size_t ws_size,
                              hipStream_t stream) {
    const float* feat  = (const float*)d_in[0];
    const int*   src   = (const int*)d_in[1];
    const int*   dst   = (const int*)d_in[2];
    const float* Wsgc  = (const float*)d_in[3];
    const float* Wlin  = (const float*)d_in[4];
    const float* Wproj = (const float*)d_in[5];
    float* out = (float*)d_out;
    char* ws = (char*)d_ws;

    int*      deg   = (int*)(ws + 0);
    int*      start = (int*)(ws + 200192);
    float*    norm  = (float*)(ws + 400384);
    int*      bcnt  = (int*)(ws + 600576);
    int*      boff  = (int*)(ws + 601600);
    int*      bcur  = (int*)(ws + 602624);
    float*    M     = (float*)(ws + 603648);
    int*      col   = (int*)(ws + 634368);
    unsigned* pairs = (unsigned*)(ws + 3834368);
    float*    x1    = (float*)(ws + 7034368);
    float*    y     = (float*)(ws + 15034368);
    float*    z1    = (float*)(ws + 23034368);

    hipMemsetAsync(bcnt, 0, NB * sizeof(int), stream);

    make_m<<<(2 * NC * NF + 255) / 256, 256, 0, stream>>>(Wsgc, Wlin, Wproj, M);
    edge_hist<<<NBLK, 256, 0, stream>>>(dst, bcnt);
    scan_buckets<<<1, 256, 0, stream>>>(bcnt, boff, bcur);
    partition<<<NBLK, 256, 0, stream>>>(src, dst, bcur, pairs);
    build_bucket<<<NB, 256, 0, stream>>>(pairs, boff, deg, start, norm, col);
    proj<<<(NN + 127) / 128, 256, 0, stream>>>(feat, M, norm, x1, y);
    spmm_sum<0><<<(NN * 8 + 255) / 256, 256, 0, stream>>>(y, z1, nullptr, norm, start, deg, col);
    spmm_sum<1><<<(NN * 8 + 255) / 256, 256, 0, stream>>>(z1, out, x1, norm, start, deg, col);
}